// Round 2
// 419.161 us; speedup vs baseline: 1.0087x; 1.0087x over previous
//
#include <hip/hip_runtime.h>
#include <hip/hip_bf16.h>

typedef unsigned short u16;
typedef short short8 __attribute__((ext_vector_type(8)));
typedef float floatx4 __attribute__((ext_vector_type(4)));
typedef float float2v __attribute__((ext_vector_type(2)));

#define BB 32
#define TT 64
#define VV 30000
#define EE 64
#define HH 64
#define OO 7
#define KSPLIT 32
#define NU32 937        /* full 32-wide k units: 937*32 = 29984, tail 16 */

__device__ __forceinline__ u16 f2b(float f) {   // fp32 -> bf16, round-to-nearest-even
    unsigned u = __float_as_uint(f);
    u += 0x7FFFu + ((u >> 16) & 1u);
    return (u16)(u >> 16);
}

// pack hi16(fe), hi16(fo) -> one VGPR via v_perm_b32 (bf16 truncation)
__device__ __forceinline__ unsigned pk2(float fo, float fe) {
    return __builtin_amdgcn_perm(__float_as_uint(fo), __float_as_uint(fe), 0x07060302u);
}

__device__ __forceinline__ float sigmoid_f(float x) {
    return 1.f / (1.f + __expf(-x));
}

__device__ __forceinline__ float tanh_f(float x) {
    float a = fabsf(x);
    float e = __expf(-2.f * a);
    float t = (1.f - e) / (1.f + e);
    return x < 0.f ? -t : t;
}

// ---------------- Kernel T: VE (V x E fp32) -> fragment-major bf16 VTf ----
// VTf chunk u (4 KB): [nb 0..3][r15 0..15][k 0..31] = B[k = u*32+k][n = nb*16+r15]
// chunks u = 0..937; u=937 has k>=16 zero-padded (and v>=30000 zero).
__global__ __launch_bounds__(256) void kT(const float* __restrict__ VE, u16* __restrict__ VTf) {
    __shared__ u16 tile[64][72];
    int v0 = blockIdx.x * 64;
    int t = threadIdx.x;
    #pragma unroll
    for (int it = 0; it < 4; ++it) {
        int c = it * 256 + t;                // 1024 float4 chunks: 64 rows x 16 chunks
        int row = c >> 4, col4 = (c & 15) * 4;
        ushort4 s; s.x = 0; s.y = 0; s.z = 0; s.w = 0;
        if (v0 + row < VV) {
            float4 d = *(const float4*)(VE + (size_t)(v0 + row) * EE + col4);
            s.x = f2b(d.x); s.y = f2b(d.y); s.z = f2b(d.z); s.w = f2b(d.w);
        }
        *(ushort4*)&tile[row][col4] = s;
    }
    __syncthreads();
    int e = t & 63;
    int nb = e >> 4, r = e & 15;
    #pragma unroll
    for (int half = 0; half < 2; ++half) {
        int q8 = (t >> 6) + half * 4;        // 0..7 -> v-local = q8*8 .. +7
        int u = (v0 >> 5) + (q8 >> 2);
        int kin = (q8 & 3) * 8;
        u16 tmp[8];
        #pragma unroll
        for (int jj = 0; jj < 8; ++jj) tmp[jj] = tile[q8 * 8 + jj][e];
        *(uint4*)&VTf[(size_t)u * 2048 + nb * 512 + r * 32 + kin] = *(uint4*)tmp;
    }
}

// ---------------- Kernel E: embed GEMM (split-K, no LDS, no barriers) + fused row-sum ----------
__global__ __launch_bounds__(256) void kE(const float* __restrict__ x, const u16* __restrict__ vtf,
                                          float* __restrict__ Cpart, float* __restrict__ Rpart) {
    int tid = threadIdx.x;
    int w = tid >> 6, l = tid & 63;
    int r15 = l & 15, q = l >> 4;
    int mb = blockIdx.x, kb = blockIdx.y;
    int m0 = mb * 64;
    int wr = m0 + w * 16;                    // this wave's 16 m-rows
    int u0 = (kb * NU32) / KSPLIT, u1 = ((kb + 1) * NU32) / KSPLIT;

    const float* aP = x + (size_t)(wr + r15) * VV + u0 * 32 + q * 8;
    const u16*   bP = vtf + (size_t)u0 * 2048 + r15 * 32 + q * 8;

    floatx4 acc[4] = {};
    floatx4 accS = {};
    short8 ones;
    #pragma unroll
    for (int i = 0; i < 8; ++i) ones[i] = (short)0x3F80;   // bf16 1.0

    #pragma unroll 4
    for (int u = u0; u < u1; ++u) {
        float4 a0 = *(const float4*)(aP);
        float4 a1 = *(const float4*)(aP + 4);
        short8 bf0 = *(const short8*)(bP);
        short8 bf1 = *(const short8*)(bP + 512);    // +1024 B -> immediate offset
        short8 bf2 = *(const short8*)(bP + 1024);
        short8 bf3 = *(const short8*)(bP + 1536);
        short8 af;
        unsigned* afu = (unsigned*)&af;
        afu[0] = pk2(a0.y, a0.x);
        afu[1] = pk2(a0.w, a0.z);
        afu[2] = pk2(a1.y, a1.x);
        afu[3] = pk2(a1.w, a1.z);
        acc[0] = __builtin_amdgcn_mfma_f32_16x16x32_bf16(af, bf0, acc[0], 0, 0, 0);
        acc[1] = __builtin_amdgcn_mfma_f32_16x16x32_bf16(af, bf1, acc[1], 0, 0, 0);
        acc[2] = __builtin_amdgcn_mfma_f32_16x16x32_bf16(af, bf2, acc[2], 0, 0, 0);
        acc[3] = __builtin_amdgcn_mfma_f32_16x16x32_bf16(af, bf3, acc[3], 0, 0, 0);
        accS   = __builtin_amdgcn_mfma_f32_16x16x32_bf16(af, ones, accS, 0, 0, 0);
        aP += 32;
        bP += 2048;
    }

    if (kb == KSPLIT - 1) {
        // K-tail u=937: A has 16 real k (q<2); B chunk is pre-zero-padded by kT
        short8 af;
        #pragma unroll
        for (int i = 0; i < 8; ++i) af[i] = 0;
        if (q < 2) {
            float4 a0 = *(const float4*)(aP);
            float4 a1 = *(const float4*)(aP + 4);
            unsigned* afu = (unsigned*)&af;
            afu[0] = pk2(a0.y, a0.x);
            afu[1] = pk2(a0.w, a0.z);
            afu[2] = pk2(a1.y, a1.x);
            afu[3] = pk2(a1.w, a1.z);
        }
        short8 bf0 = *(const short8*)(bP);
        short8 bf1 = *(const short8*)(bP + 512);
        short8 bf2 = *(const short8*)(bP + 1024);
        short8 bf3 = *(const short8*)(bP + 1536);
        acc[0] = __builtin_amdgcn_mfma_f32_16x16x32_bf16(af, bf0, acc[0], 0, 0, 0);
        acc[1] = __builtin_amdgcn_mfma_f32_16x16x32_bf16(af, bf1, acc[1], 0, 0, 0);
        acc[2] = __builtin_amdgcn_mfma_f32_16x16x32_bf16(af, bf2, acc[2], 0, 0, 0);
        acc[3] = __builtin_amdgcn_mfma_f32_16x16x32_bf16(af, bf3, acc[3], 0, 0, 0);
        accS   = __builtin_amdgcn_mfma_f32_16x16x32_bf16(af, ones, accS, 0, 0, 0);
    }

    // epilogue: C/D layout is col = lane&15, row = (lane>>4)*4 + reg
    float* Cp = Cpart + (size_t)kb * (2048 * 64);
    #pragma unroll
    for (int r = 0; r < 4; ++r) {
        int row = wr + q * 4 + r;
        #pragma unroll
        for (int n = 0; n < 4; ++n)
            Cp[(size_t)row * 64 + n * 16 + r15] = acc[n][r];
        if (r15 == 0) Rpart[kb * 2048 + row] = accS[r];
    }
}

// ---------------- Kernel R: full-grid split-K reduce + embed-finish + 3 gate GEMMs ------------
// 128 blocks x 16 rows. Fixes the old kGS phase-1 problem: Cpart's 16.7 MB was reduced by only
// 32 resident blocks (32/256 CUs -> ~21 us); here 128 blocks do it at ~4x the BW, and the
// 12 (gate,nb) MFMA units are spread over all 4 waves. Output: X[3][2048][64] fp32 (1.57 MB).
__global__ __launch_bounds__(256) void kR(const float* __restrict__ Cpart, const float* __restrict__ Rpart,
                                          const float* __restrict__ Wir, const float* __restrict__ Wiz,
                                          const float* __restrict__ Win,
                                          const float* __restrict__ bir, const float* __restrict__ biz,
                                          const float* __restrict__ bin,
                                          float* __restrict__ X) {
    __shared__ float rsinv[16];
    __shared__ u16 eL[16 * 72];
    int tid = threadIdx.x;
    int m0 = blockIdx.x * 16;

    if (tid < 16) {
        float rs = 0.f;
        #pragma unroll
        for (int kb = 0; kb < KSPLIT; ++kb)
            rs += Rpart[kb * 2048 + m0 + tid];
        rsinv[tid] = 1.f / rs;
    }

    // split-K reduce: per kb the 16-row tile is 4 KB contiguous; thread owns one float4 cell
    float4 a; a.x = 0.f; a.y = 0.f; a.z = 0.f; a.w = 0.f;
    const float* cp = Cpart + (size_t)m0 * 64 + tid * 4;
    #pragma unroll 8
    for (int kb = 0; kb < KSPLIT; ++kb) {
        float4 v = *(const float4*)(cp + (size_t)kb * (2048 * 64));
        a.x += v.x; a.y += v.y; a.z += v.z; a.w += v.w;
    }
    __syncthreads();
    {
        int row = tid >> 4;
        float ri = rsinv[row];
        float e0 = a.x * ri, e1 = a.y * ri, e2 = a.z * ri, e3 = a.w * ri;
        e0 = e0 > 0.f ? e0 : 0.f;  e1 = e1 > 0.f ? e1 : 0.f;
        e2 = e2 > 0.f ? e2 : 0.f;  e3 = e3 > 0.f ? e3 : 0.f;
        ushort4 s;
        s.x = f2b(e0); s.y = f2b(e1); s.z = f2b(e2); s.w = f2b(e3);
        *(ushort4*)&eL[row * 72 + (tid & 15) * 4] = s;
    }
    __syncthreads();

    // gate GEMMs: 16x16x32 MFMA, M=16 (A-frag row = lane&15), K=64 -> 2 MFMAs per unit.
    // 12 units (g,nb) split 3-per-wave.
    int w = tid >> 6, l = tid & 63;
    int r15 = l & 15, q = l >> 4;
    short8 fa0 = *(const short8*)&eL[r15 * 72 + q * 8];
    short8 fa1 = *(const short8*)&eL[r15 * 72 + 32 + q * 8];

    #pragma unroll
    for (int un = 0; un < 3; ++un) {
        int u = w * 3 + un;
        int g = u >> 2, nb = u & 3;
        const float* W  = (g == 0) ? Wir : (g == 1) ? Wiz : Win;
        const float* bo = (g == 0) ? bir : (g == 1) ? biz : bin;
        const float* wrow = W + (nb * 16 + r15) * 64 + q * 8;
        float4 w0 = *(const float4*)(wrow);
        float4 w1 = *(const float4*)(wrow + 4);
        float4 w2 = *(const float4*)(wrow + 32);
        float4 w3 = *(const float4*)(wrow + 36);
        short8 b0, b1;
        unsigned* b0u = (unsigned*)&b0; unsigned* b1u = (unsigned*)&b1;
        b0u[0] = pk2(w0.y, w0.x); b0u[1] = pk2(w0.w, w0.z);
        b0u[2] = pk2(w1.y, w1.x); b0u[3] = pk2(w1.w, w1.z);
        b1u[0] = pk2(w2.y, w2.x); b1u[1] = pk2(w2.w, w2.z);
        b1u[2] = pk2(w3.y, w3.x); b1u[3] = pk2(w3.w, w3.z);
        floatx4 acc = {};
        acc = __builtin_amdgcn_mfma_f32_16x16x32_bf16(fa0, b0, acc, 0, 0, 0);
        acc = __builtin_amdgcn_mfma_f32_16x16x32_bf16(fa1, b1, acc, 0, 0, 0);
        float bias = bo[nb * 16 + r15];
        #pragma unroll
        for (int r = 0; r < 4; ++r) {
            int row = q * 4 + r;               // C/D: col = lane&15, row = q*4 + reg
            X[((size_t)g * 2048 + m0 + row) * 64 + nb * 16 + r15] = acc[r] + bias;
        }
    }
}

// ---------------- Kernel S: pure GRU scan, one wave per batch ----------------------------------
// Replaces the 64 v_readlane/step with 1 ds_write + 16 broadcast ds_read_b128 (same-wave LDS is
// in-order; same-address reads broadcast conflict-free), and float2 math so the compiler can
// emit v_pk_fma_f32 (64 packed vs 128 scalar FMA per step).
__global__ __launch_bounds__(64) void kS(const float* __restrict__ X,
                                         const float* __restrict__ Whr, const float* __restrict__ Whz,
                                         const float* __restrict__ bhr, const float* __restrict__ bhz,
                                         const float* __restrict__ Wout, const float* __restrict__ bout,
                                         float* __restrict__ out) {
    __shared__ __align__(16) float Xs[3][64][64];
    __shared__ __align__(16) float hbc[64];
    int i = threadIdx.x;
    int b = blockIdx.x;

    // stage this batch's 48 KB gate slab into LDS (mostly L2/L3-resident, just written by kR)
    const float* src = X + (size_t)b * 64 * 64;
    #pragma unroll
    for (int g = 0; g < 3; ++g) {
        const float4* s4 = (const float4*)(src + (size_t)g * 2048 * 64);
        float4* d4 = (float4*)&Xs[g][0][0];
        #pragma unroll
        for (int c = 0; c < 16; ++c)
            d4[c * 64 + i] = s4[c * 64 + i];
    }

    // recurrent weights in registers as float2 pairs: lane i owns row i of Whr/Whz
    float2v wr2[32], wz2[32];
    #pragma unroll
    for (int c = 0; c < 16; ++c) {
        float4 v1 = *(const float4*)(Whr + i * 64 + c * 4);
        float4 v2 = *(const float4*)(Whz + i * 64 + c * 4);
        float2v a01 = {v1.x, v1.y}, a23 = {v1.z, v1.w};
        float2v b01 = {v2.x, v2.y}, b23 = {v2.z, v2.w};
        wr2[c * 2] = a01; wr2[c * 2 + 1] = a23;
        wz2[c * 2] = b01; wz2[c * 2 + 1] = b23;
    }
    float bri = bhr[i], bzi = bhz[i];
    __syncthreads();

    // h0 from t=0 gates (z,n); r-gate at t=0 unused (matches reference)
    float h;
    {
        float z1 = sigmoid_f(Xs[1][0][i]);
        float n1 = tanh_f(Xs[2][0][i]);
        h = (1.f - z1) * n1;
    }

    for (int t = 1; t < 64; ++t) {
        hbc[i] = h;                           // one ds_write; wave-internal LDS is in program order
        float xr = Xs[0][t][i], xz = Xs[1][t][i], xn = Xs[2][t][i];
        float2v ar0 = {0.f, 0.f}, ar1 = {0.f, 0.f};
        float2v az0 = {0.f, 0.f}, az1 = {0.f, 0.f};
        #pragma unroll
        for (int j = 0; j < 64; j += 4) {
            float4 hv = *(const float4*)&hbc[j];   // broadcast read, conflict-free
            float2v hA = {hv.x, hv.y}, hB = {hv.z, hv.w};
            ar0 += hA * wr2[j >> 1]; ar1 += hB * wr2[(j >> 1) + 1];
            az0 += hA * wz2[j >> 1]; az1 += hB * wz2[(j >> 1) + 1];
        }
        float hr = bri + ((ar0.x + ar0.y) + (ar1.x + ar1.y));
        float hz = bzi + ((az0.x + az0.y) + (az1.x + az1.y));
        float r = sigmoid_f(xr + hr);
        float z = sigmoid_f(xz + hz);
        float n = tanh_f(xn + r * hr);        // ref uses r*hr: W_hn/b_hn are dead
        h = (1.f - z) * n + z * h;
    }

    hbc[i] = h;
    if (i < OO) {
        float a = bout[i];
        #pragma unroll 8
        for (int j = 0; j < 64; ++j)
            a += hbc[j] * Wout[i * 64 + j];
        out[b * OO + i] = a;
    }
}

extern "C" void kernel_launch(void* const* d_in, const int* in_sizes, int n_in,
                              void* d_out, int out_size, void* d_ws, size_t ws_size,
                              hipStream_t stream) {
    const float* x    = (const float*)d_in[0];
    const float* VE   = (const float*)d_in[1];
    const float* Wir  = (const float*)d_in[2];
    const float* Wiz  = (const float*)d_in[3];
    const float* Win  = (const float*)d_in[4];
    const float* Whr  = (const float*)d_in[5];
    const float* Whz  = (const float*)d_in[6];
    // d_in[7] = W_hn (dead in the reference recurrence)
    const float* bir  = (const float*)d_in[8];
    const float* biz  = (const float*)d_in[9];
    const float* bin  = (const float*)d_in[10];
    const float* bhr  = (const float*)d_in[11];
    const float* bhz  = (const float*)d_in[12];
    // d_in[13] = b_hn (dead)
    const float* Wout = (const float*)d_in[14];
    const float* bout = (const float*)d_in[15];

    char* ws = (char*)d_ws;
    u16*   VTf   = (u16*)(ws);                              //  938*4096 = 3,842,048 B
    float* Cpart = (float*)(ws + 4000000);                  // 16,777,216 B
    float* Rpart = (float*)(ws + 20777216);                 //    262,144 B
    float* Xg    = (float*)(ws + 21039360);                 //  1,572,864 B (3 x 2048 x 64 fp32)

    kT<<<469, 256, 0, stream>>>(VE, VTf);                   // 469*64 = 30016 v's (pad zeroed)
    kE<<<dim3(2048 / 64, KSPLIT), 256, 0, stream>>>(x, VTf, Cpart, Rpart);
    kR<<<128, 256, 0, stream>>>(Cpart, Rpart, Wir, Wiz, Win, bir, biz, bin, Xg);
    kS<<<BB, 64, 0, stream>>>(Xg, Whr, Whz, bhr, bhz, Wout, bout, (float*)d_out);
}